// Round 3
// baseline (803.919 us; speedup 1.0000x reference)
//
#include <hip/hip_runtime.h>
#include <hip/hip_fp16.h>

#define S_LEN 4096
#define NT 256
#define RANK 8
#define AP 4352   // padded FFT scratch (transpose-2 max addr 4350)

__device__ __forceinline__ void cmul(float& xr, float& xi, float cr, float ci){
    float tr = xr*cr - xi*ci;
    xi = xr*ci + xi*cr;
    xr = tr;
}

template<int SIGN>
__device__ __forceinline__ void dft4(float& ar,float& ai,float& br,float& bi,
                                     float& cr,float& ci,float& dr,float& di){
    float Ar=ar+cr, Ai=ai+ci;
    float Br=ar-cr, Bi=ai-ci;
    float Cr=br+dr, Ci=bi+di;
    float Dr, Di;
    if (SIGN < 0){ Dr = bi-di; Di = dr-br; }
    else         { Dr = di-bi; Di = br-dr; }
    ar=Ar+Cr; ai=Ai+Ci;
    br=Br+Dr; bi=Bi+Di;
    cr=Ar-Cr; ci=Ai-Ci;
    dr=Br-Dr; di=Bi-Di;
}

// 16-pt DFT in regs; input natural order, output X[k] at slot 4*(k&3)+(k>>2)
template<int SIGN>
__device__ __forceinline__ void dft16(float ur[16], float ui[16]){
    constexpr float TC[10] = {1.0f, 0.92387953251128674f, 0.70710678118654752f,
                              0.38268343236508977f, 0.0f, -0.38268343236508977f,
                              -0.70710678118654752f, -0.92387953251128674f, -1.0f,
                              -0.92387953251128674f};
    constexpr float TS[10] = {0.0f, 0.38268343236508977f, 0.70710678118654752f,
                              0.92387953251128674f, 1.0f, 0.92387953251128674f,
                              0.70710678118654752f, 0.38268343236508977f, 0.0f,
                              -0.38268343236508977f};
#pragma unroll
    for (int p=0;p<4;p++)
        dft4<SIGN>(ur[p],ui[p], ur[p+4],ui[p+4], ur[p+8],ui[p+8], ur[p+12],ui[p+12]);
#pragma unroll
    for (int j=1;j<4;j++){
#pragma unroll
        for (int p=1;p<4;p++){
            const int e = p*j;
            const float c = TC[e];
            const float s = (SIGN < 0) ? -TS[e] : TS[e];
            cmul(ur[4*j+p], ui[4*j+p], c, s);
        }
    }
#pragma unroll
    for (int j=0;j<4;j++)
        dft4<SIGN>(ur[4*j+0],ui[4*j+0], ur[4*j+1],ui[4*j+1],
                   ur[4*j+2],ui[4*j+2], ur[4*j+3],ui[4*j+3]);
}

template<int SIGN>
__device__ __forceinline__ void twiddle_powers(float ur[16], float ui[16], float theta){
    float s, c;
    __sincosf(theta, &s, &c);
    const float wi = (SIGN < 0) ? -s : s;
    const float wr = c;
    float pr = wr, pi = wi;
    cmul(ur[1], ui[1], pr, pi);
#pragma unroll
    for (int m=2;m<16;m++){
        float nr = pr*wr - pi*wi;
        pi = pr*wi + pi*wr;
        pr = nr;
        cmul(ur[m], ui[m], pr, pi);
    }
}

__global__ __launch_bounds__(NT, 3) void recip_mixer(
    const float* __restrict__ x,
    const float* __restrict__ Ur, const float* __restrict__ Ui,
    const float* __restrict__ Vr, const float* __restrict__ Vi,
    const float* __restrict__ Wr, const float* __restrict__ Wi,
    const float* __restrict__ P1w, const float* __restrict__ P1b,
    const float* __restrict__ P2w, const float* __restrict__ P2b,
    const float* __restrict__ alphap,
    float* __restrict__ out)
{
    __shared__ float sre[AP], sim[AP];
    __shared__ __half ga16[S_LEN], gb16[S_LEN];
    __shared__ float red[256];
    __shared__ float hid[2 * RANK];
    __shared__ float gam[4 * RANK];

    const int t    = threadIdx.x;
    const int pair = blockIdx.x;           // rows 2*pair, 2*pair+1
    const int lane = t & 63;
    const int wid  = t >> 6;

    float ur[16], ui[16];

    // ============ forward FFT of c = xa + i*xb (one FFT, two rows) ============
    {
        const float* xa = x + (size_t)(2 * pair) * S_LEN;
        const float* xb = xa + S_LEN;
#pragma unroll
        for (int c=0;c<16;c++){ ur[c] = xa[t + 256*c]; ui[c] = xb[t + 256*c]; }
        dft16<-1>(ur, ui);
        const int base1 = (t & 15) + 272 * (t >> 4);
#pragma unroll
        for (int k=0;k<16;k++){
            const int slot = 4*(k&3) + (k>>2);
            sre[base1 + 16*k] = ur[slot];
            sim[base1 + 16*k] = ui[slot];
        }
    }
    __syncthreads();
    {
        const int n1 = t & 15, k2p = t >> 4;
#pragma unroll
        for (int m=0;m<16;m++){
            ur[m] = sre[n1 + 272*m + 16*k2p];
            ui[m] = sim[n1 + 272*m + 16*k2p];
        }
        twiddle_powers<-1>(ur, ui, 6.2831853071795864769f * (float)k2p * (1.0f/256.0f));
        dft16<-1>(ur, ui);
        __syncthreads();
        const int base2 = k2p + 17*n1;
#pragma unroll
        for (int k=0;k<16;k++){
            const int slot = 4*(k&3) + (k>>2);
            sre[base2 + 272*k] = ur[slot];
            sim[base2 + 272*k] = ui[slot];
        }
    }
    __syncthreads();
    {
#pragma unroll
        for (int m=0;m<16;m++){
            ur[m] = sre[(t&15) + 17*m + 272*(t>>4)];
            ui[m] = sim[(t&15) + 17*m + 272*(t>>4)];
        }
        twiddle_powers<-1>(ur, ui, 6.2831853071795864769f * (float)t * (1.0f/4096.0f));
        dft16<-1>(ur, ui);
        __syncthreads();
        // write Z linear (keep register copy for phase 1)
#pragma unroll
        for (int k=0;k<16;k++){
            const int slot = 4*(k&3) + (k>>2);
            sre[t + 256*k] = ur[slot];
            sim[t + 256*k] = ui[slot];
        }
    }
    __syncthreads();

    // ============ M1: hidden = relu(P1w @ [Re X ; Im X] + P1b), both rows ====
    {
        float h[16];
#pragma unroll
        for (int j=0;j<16;j++) h[j] = 0.0f;
#pragma unroll
        for (int k1=0;k1<16;k1++){
            const int k   = t + 256*k1;
            const int rev = (S_LEN - k) & (S_LEN - 1);
            const int slot = 4*(k1&3) + (k1>>2);
            const float ZkR = ur[slot], ZkI = ui[slot];
            const float ZrR = sre[rev], ZrI = sim[rev];
            const float XaR = 0.5f*(ZkR + ZrR), XaI = 0.5f*(ZkI - ZrI);
            const float XbR = 0.5f*(ZkI + ZrI), XbI = 0.5f*(ZrR - ZkR);
#pragma unroll
            for (int r=0;r<RANK;r++){
                const float w1 = P1w[r * (2*S_LEN) + k];
                const float w2 = P1w[r * (2*S_LEN) + S_LEN + k];
                h[r]     += XaR * w1 + XaI * w2;
                h[8 + r] += XbR * w1 + XbI * w2;
            }
        }
#pragma unroll
        for (int j=0;j<16;j++){
#pragma unroll
            for (int off = 32; off > 0; off >>= 1)
                h[j] += __shfl_xor(h[j], off, 64);
        }
        if (lane == 0){
#pragma unroll
            for (int j=0;j<16;j++) red[wid*16 + j] = h[j];
        }
        __syncthreads();
        if (t < 16){
            float v = red[t] + red[16 + t] + red[32 + t] + red[48 + t];
            hid[t] = fmaxf(v + P1b[t & 7], 0.0f);
        }
        __syncthreads();
    }

    // ============ M2: gains + p/q rank-8 accumulation, both rows =============
    {
        float hha[RANK], hhb[RANK];
#pragma unroll
        for (int r=0;r<RANK;r++){ hha[r] = hid[r]; hhb[r] = hid[8 + r]; }
        const float alpha = alphap[0];

        float acc[64];   // [par,pai,qar,qai,pbr,pbi,qbr,qbi] x 8
#pragma unroll
        for (int j=0;j<64;j++) acc[j] = 0.0f;

#pragma unroll
        for (int k1=0;k1<16;k1++){
            const int k   = t + 256*k1;
            const int rev = (S_LEN - k) & (S_LEN - 1);
            const float ZkR = sre[k],   ZkI = sim[k];
            const float ZrR = sre[rev], ZrI = sim[rev];
            const float XaR = 0.5f*(ZkR + ZrR), XaI = 0.5f*(ZkI - ZrI);
            const float XbR = 0.5f*(ZkI + ZrI), XbI = 0.5f*(ZrR - ZkR);

            const int m = (k < S_LEN - k) ? k : (S_LEN - k);
            const float nf = (float)(2 * m) * (1.0f / (float)S_LEN);
            const float tt = nf * 5.0f;
            const float lb = __expf(-0.5f * tt * tt);
            const float hd = 0.5f / (1.0f + __expf(-(nf - 0.6f) * 10.0f));
            const float bg = fmaxf(1.0f + lb - hd, 0.0f);

            const float scaled = nf * 4095.0f;
            const float fl = floorf(scaled);
            const int   lo = (int)fl;
            const int   hi = (int)ceilf(scaled);
            const float fr = scaled - fl;

            const float4* p2lo = (const float4*)(P2w + (size_t)lo * RANK);
            const float4* p2hi = (const float4*)(P2w + (size_t)hi * RANK);
            const float4 a0 = p2lo[0], a1 = p2lo[1];
            const float4 b0 = p2hi[0], b1 = p2hi[1];
            const float blo = P2b[lo], bhi = P2b[hi];

            const float dlo_a = blo + hha[0]*a0.x + hha[1]*a0.y + hha[2]*a0.z + hha[3]*a0.w
                                    + hha[4]*a1.x + hha[5]*a1.y + hha[6]*a1.z + hha[7]*a1.w;
            const float dhi_a = bhi + hha[0]*b0.x + hha[1]*b0.y + hha[2]*b0.z + hha[3]*b0.w
                                    + hha[4]*b1.x + hha[5]*b1.y + hha[6]*b1.z + hha[7]*b1.w;
            const float dlo_b = blo + hhb[0]*a0.x + hhb[1]*a0.y + hhb[2]*a0.z + hhb[3]*a0.w
                                    + hhb[4]*a1.x + hhb[5]*a1.y + hhb[6]*a1.z + hhb[7]*a1.w;
            const float dhi_b = bhi + hhb[0]*b0.x + hhb[1]*b0.y + hhb[2]*b0.z + hhb[3]*b0.w
                                    + hhb[4]*b1.x + hhb[5]*b1.y + hhb[6]*b1.z + hhb[7]*b1.w;

            const float ga = fmaxf(bg + alpha * (dlo_a + (dhi_a - dlo_a) * fr), 0.0f);
            const float gb = fmaxf(bg + alpha * (dlo_b + (dhi_b - dlo_b) * fr), 0.0f);
            ga16[k] = __float2half(ga);
            gb16[k] = __float2half(gb);

            const float zaR = ga * XaR, zaI = ga * XaI;
            const float zbR = gb * XbR, zbI = gb * XbI;

#pragma unroll
            for (int r=0;r<RANK;r++){
                const float uR = Ur[r * S_LEN + k], uI = Ui[r * S_LEN + k];
                const float vR = Vr[r * S_LEN + k], vI = Vi[r * S_LEN + k];
                acc[r]      += zaR * uR - zaI * uI;
                acc[8 + r]  += zaR * uI + zaI * uR;
                acc[16 + r] += zaR * vR - zaI * vI;
                acc[24 + r] += zaR * vI + zaI * vR;
                acc[32 + r] += zbR * uR - zbI * uI;
                acc[40 + r] += zbR * uI + zbI * uR;
                acc[48 + r] += zbR * vR - zbI * vI;
                acc[56 + r] += zbR * vI + zbI * vR;
            }
        }

#pragma unroll
        for (int j=0;j<64;j++){
#pragma unroll
            for (int off = 32; off > 0; off >>= 1)
                acc[j] += __shfl_xor(acc[j], off, 64);
        }
        if (lane == 0){
#pragma unroll
            for (int j=0;j<64;j++) red[wid*64 + j] = acc[j];
        }
        __syncthreads();
        if (t < 64){
            red[t] = red[t] + red[64 + t] + red[128 + t] + red[192 + t];
        }
        __syncthreads();
        if (t < RANK){
            const float paR = red[t],      paI = red[8 + t];
            const float qaR = red[16 + t], qaI = red[24 + t];
            const float pbR = red[32 + t], pbI = red[40 + t];
            const float qbR = red[48 + t], qbI = red[56 + t];
            gam[t]          = paR * qaR + paI * qaI;   // Re gamma_a
            gam[8 + t]      = paI * qaR - paR * qaI;   // Im gamma_a
            gam[16 + t]     = pbR * qbR + pbI * qbI;   // Re gamma_b
            gam[24 + t]     = pbI * qbR - pbR * qbI;   // Im gamma_b
        }
        __syncthreads();
    }

    // ============ M4: w = ((ga+gb)Z + (ga-gb)conj(Zrev))/2 + HermDa + i*HermDb
    {
        float gaR[RANK], gaI[RANK], gbR[RANK], gbI[RANK];
#pragma unroll
        for (int r=0;r<RANK;r++){
            gaR[r] = gam[r];      gaI[r] = gam[8 + r];
            gbR[r] = gam[16 + r]; gbI[r] = gam[24 + r];
        }
        const float4* Wr4 = (const float4*)Wr;
        const float4* Wi4 = (const float4*)Wi;

#pragma unroll
        for (int k1=0;k1<16;k1++){
            const int k   = t + 256*k1;
            const int rev = (S_LEN - k) & (S_LEN - 1);
            const float ZkR = sre[k],   ZkI = sim[k];
            const float ZrR = sre[rev], ZrI = sim[rev];
            const float ga = __half2float(ga16[k]);
            const float gb = __half2float(gb16[k]);
            const float c1 = 0.5f * (ga + gb);
            const float c2 = 0.5f * (ga - gb);
            float wR = c1 * ZkR + c2 * ZrR;
            float wI = c1 * ZkI - c2 * ZrI;

            const float4 ka0 = Wr4[k*2],   ka1 = Wr4[k*2+1];
            const float4 kb0 = Wi4[k*2],   kb1 = Wi4[k*2+1];
            const float4 ra0 = Wr4[rev*2], ra1 = Wr4[rev*2+1];
            const float4 rb0 = Wi4[rev*2], rb1 = Wi4[rev*2+1];
            const float wrk[RANK] = { ka0.x,ka0.y,ka0.z,ka0.w, ka1.x,ka1.y,ka1.z,ka1.w };
            const float wik[RANK] = { kb0.x,kb0.y,kb0.z,kb0.w, kb1.x,kb1.y,kb1.z,kb1.w };
            const float wrr[RANK] = { ra0.x,ra0.y,ra0.z,ra0.w, ra1.x,ra1.y,ra1.z,ra1.w };
            const float wir[RANK] = { rb0.x,rb0.y,rb0.z,rb0.w, rb1.x,rb1.y,rb1.z,rb1.w };

            float aR=0.f, aI=0.f, arR=0.f, arI=0.f;
            float bR=0.f, bI=0.f, brR=0.f, brI=0.f;
#pragma unroll
            for (int r=0;r<RANK;r++){
                aR  += gaR[r]*wrk[r] - gaI[r]*wik[r];
                aI  += gaR[r]*wik[r] + gaI[r]*wrk[r];
                arR += gaR[r]*wrr[r] - gaI[r]*wir[r];
                arI += gaR[r]*wir[r] + gaI[r]*wrr[r];
                bR  += gbR[r]*wrk[r] - gbI[r]*wik[r];
                bI  += gbR[r]*wik[r] + gbI[r]*wrk[r];
                brR += gbR[r]*wrr[r] - gbI[r]*wir[r];
                brI += gbR[r]*wir[r] + gbI[r]*wrr[r];
            }
            // HermDa = ((aR+arR)/2, (aI-arI)/2); HermDb = ((bR+brR)/2, (bI-brI)/2)
            wR += 0.5f * (aR + arR) - 0.5f * (bI - brI);
            wI += 0.5f * (aI - arI) + 0.5f * (bR + brR);
            ur[k1] = wR;
            ui[k1] = wI;
        }
    }

    // ============ inverse FFT of w: row a = Re, row b = Im ====================
    dft16<1>(ur, ui);
    __syncthreads();   // all Z/gain reads done before scratch overwrite
    {
        const int base1 = (t & 15) + 272 * (t >> 4);
#pragma unroll
        for (int k=0;k<16;k++){
            const int slot = 4*(k&3) + (k>>2);
            sre[base1 + 16*k] = ur[slot];
            sim[base1 + 16*k] = ui[slot];
        }
    }
    __syncthreads();
    {
        const int a = t & 15, b = t >> 4;
#pragma unroll
        for (int m=0;m<16;m++){
            ur[m] = sre[a + 272*m + 16*b];
            ui[m] = sim[a + 272*m + 16*b];
        }
        twiddle_powers<1>(ur, ui, 6.2831853071795864769f * (float)b * (1.0f/256.0f));
        dft16<1>(ur, ui);
        __syncthreads();
        const int base2 = b + 17*a;
#pragma unroll
        for (int k=0;k<16;k++){
            const int slot = 4*(k&3) + (k>>2);
            sre[base2 + 272*k] = ur[slot];
            sim[base2 + 272*k] = ui[slot];
        }
    }
    __syncthreads();
    {
#pragma unroll
        for (int m=0;m<16;m++){
            ur[m] = sre[(t&15) + 17*m + 272*(t>>4)];
            ui[m] = sim[(t&15) + 17*m + 272*(t>>4)];
        }
        twiddle_powers<1>(ur, ui, 6.2831853071795864769f * (float)t * (1.0f/4096.0f));
        dft16<1>(ur, ui);
        float* orowA = out + (size_t)(2 * pair) * S_LEN;
        float* orowB = orowA + S_LEN;
        const float scale = 1.0f / (float)S_LEN;
#pragma unroll
        for (int k=0;k<16;k++){
            const int slot = 4*(k&3) + (k>>2);
            orowA[t + 256*k] = ur[slot] * scale;
            orowB[t + 256*k] = ui[slot] * scale;
        }
    }
}

extern "C" void kernel_launch(void* const* d_in, const int* in_sizes, int n_in,
                              void* d_out, int out_size, void* d_ws, size_t ws_size,
                              hipStream_t stream) {
    const float* x    = (const float*)d_in[0];
    const float* Ur   = (const float*)d_in[1];
    const float* Ui   = (const float*)d_in[2];
    const float* Vr   = (const float*)d_in[3];
    const float* Vi   = (const float*)d_in[4];
    const float* Wr   = (const float*)d_in[5];
    const float* Wi   = (const float*)d_in[6];
    const float* P1w  = (const float*)d_in[7];
    const float* P1b  = (const float*)d_in[8];
    const float* P2w  = (const float*)d_in[9];
    const float* P2b  = (const float*)d_in[10];
    const float* alph = (const float*)d_in[11];

    recip_mixer<<<dim3(1024), dim3(NT), 0, stream>>>(
        x, Ur, Ui, Vr, Vi, Wr, Wi, P1w, P1b, P2w, P2b, alph, (float*)d_out);
}

// Round 4
// 300.472 us; speedup vs baseline: 2.6755x; 2.6755x over previous
//
#include <hip/hip_runtime.h>

#define S_LEN 4096
#define NT 256
#define RANK 8
#define AP 4352   // padded FFT scratch (transpose-2 max addr 4350)

__device__ __forceinline__ float rfl(float v){
    return __int_as_float(__builtin_amdgcn_readfirstlane(__float_as_int(v)));
}

__device__ __forceinline__ void cmul(float& xr, float& xi, float cr, float ci){
    float tr = xr*cr - xi*ci;
    xi = xr*ci + xi*cr;
    xr = tr;
}

template<int SIGN>
__device__ __forceinline__ void dft4(float& ar,float& ai,float& br,float& bi,
                                     float& cr,float& ci,float& dr,float& di){
    float Ar=ar+cr, Ai=ai+ci;
    float Br=ar-cr, Bi=ai-ci;
    float Cr=br+dr, Ci=bi+di;
    float Dr, Di;
    if (SIGN < 0){ Dr = bi-di; Di = dr-br; }
    else         { Dr = di-bi; Di = br-dr; }
    ar=Ar+Cr; ai=Ai+Ci;
    br=Br+Dr; bi=Bi+Di;
    cr=Ar-Cr; ci=Ai-Ci;
    dr=Br-Dr; di=Bi-Di;
}

// 16-pt DFT in regs; input natural order, output X[k] at slot 4*(k&3)+(k>>2)
template<int SIGN>
__device__ __forceinline__ void dft16(float ur[16], float ui[16]){
    constexpr float TC[10] = {1.0f, 0.92387953251128674f, 0.70710678118654752f,
                              0.38268343236508977f, 0.0f, -0.38268343236508977f,
                              -0.70710678118654752f, -0.92387953251128674f, -1.0f,
                              -0.92387953251128674f};
    constexpr float TS[10] = {0.0f, 0.38268343236508977f, 0.70710678118654752f,
                              0.92387953251128674f, 1.0f, 0.92387953251128674f,
                              0.70710678118654752f, 0.38268343236508977f, 0.0f,
                              -0.38268343236508977f};
#pragma unroll
    for (int p=0;p<4;p++)
        dft4<SIGN>(ur[p],ui[p], ur[p+4],ui[p+4], ur[p+8],ui[p+8], ur[p+12],ui[p+12]);
#pragma unroll
    for (int j=1;j<4;j++){
#pragma unroll
        for (int p=1;p<4;p++){
            const int e = p*j;
            const float c = TC[e];
            const float s = (SIGN < 0) ? -TS[e] : TS[e];
            cmul(ur[4*j+p], ui[4*j+p], c, s);
        }
    }
#pragma unroll
    for (int j=0;j<4;j++)
        dft4<SIGN>(ur[4*j+0],ui[4*j+0], ur[4*j+1],ui[4*j+1],
                   ur[4*j+2],ui[4*j+2], ur[4*j+3],ui[4*j+3]);
}

template<int SIGN>
__device__ __forceinline__ void twiddle_powers(float ur[16], float ui[16], float theta){
    float s, c;
    __sincosf(theta, &s, &c);
    const float wi = (SIGN < 0) ? -s : s;
    const float wr = c;
    float pr = wr, pi = wi;
    cmul(ur[1], ui[1], pr, pi);
#pragma unroll
    for (int m=2;m<16;m++){
        float nr = pr*wr - pi*wi;
        pi = pr*wi + pi*wr;
        pr = nr;
        cmul(ur[m], ui[m], pr, pi);
    }
}

// base spectral gain + interpolation setup shared by M2/M4
__device__ __forceinline__ void gain_setup(int k, float& bg, int& lo, int& hi, float& fr){
    const int m = (k < S_LEN - k) ? k : (S_LEN - k);
    const float nf = (float)(2 * m) * (1.0f / (float)S_LEN);
    const float tt = nf * 5.0f;
    const float lb = __expf(-0.5f * tt * tt);
    const float hd = 0.5f / (1.0f + __expf(-(nf - 0.6f) * 10.0f));
    bg = fmaxf(1.0f + lb - hd, 0.0f);
    const float scaled = nf * 4095.0f;
    const float fl = floorf(scaled);
    lo = (int)fl;
    hi = (int)ceilf(scaled);
    fr = scaled - fl;
}

__global__ __launch_bounds__(NT, 4) void recip_mixer(
    const float* __restrict__ x,
    const float* __restrict__ Ur, const float* __restrict__ Ui,
    const float* __restrict__ Vr, const float* __restrict__ Vi,
    const float* __restrict__ Wr, const float* __restrict__ Wi,
    const float* __restrict__ P1w, const float* __restrict__ P1b,
    const float* __restrict__ P2w, const float* __restrict__ P2b,
    const float* __restrict__ alphap,
    float* __restrict__ out)
{
    __shared__ float sre[AP], sim[AP];
    __shared__ float red[128];
    __shared__ float hid[2 * RANK];
    __shared__ float gam[4 * RANK];

    const int t    = threadIdx.x;
    const int pair = blockIdx.x;           // rows 2*pair, 2*pair+1
    const int lane = t & 63;
    const int wid  = t >> 6;
    const int half = t >> 7;               // 0: row a, 1: row b (wave-uniform)
    const int th   = t & 127;

    const float alpha = alphap[0];

    float ur[16], ui[16];

    // ============ forward FFT of c = xa + i*xb (one FFT, two rows) ============
    {
        const float* xa = x + (size_t)(2 * pair) * S_LEN;
        const float* xb = xa + S_LEN;
#pragma unroll
        for (int c=0;c<16;c++){ ur[c] = xa[t + 256*c]; ui[c] = xb[t + 256*c]; }
        dft16<-1>(ur, ui);
        const int base1 = (t & 15) + 272 * (t >> 4);
#pragma unroll
        for (int k=0;k<16;k++){
            const int slot = 4*(k&3) + (k>>2);
            sre[base1 + 16*k] = ur[slot];
            sim[base1 + 16*k] = ui[slot];
        }
    }
    __syncthreads();
    {
        const int n1 = t & 15, k2p = t >> 4;
#pragma unroll
        for (int m=0;m<16;m++){
            ur[m] = sre[n1 + 272*m + 16*k2p];
            ui[m] = sim[n1 + 272*m + 16*k2p];
        }
        twiddle_powers<-1>(ur, ui, 6.2831853071795864769f * (float)k2p * (1.0f/256.0f));
        dft16<-1>(ur, ui);
        __syncthreads();
        const int base2 = k2p + 17*n1;
#pragma unroll
        for (int k=0;k<16;k++){
            const int slot = 4*(k&3) + (k>>2);
            sre[base2 + 272*k] = ur[slot];
            sim[base2 + 272*k] = ui[slot];
        }
    }
    __syncthreads();
    {
#pragma unroll
        for (int m=0;m<16;m++){
            ur[m] = sre[(t&15) + 17*m + 272*(t>>4)];
            ui[m] = sim[(t&15) + 17*m + 272*(t>>4)];
        }
        twiddle_powers<-1>(ur, ui, 6.2831853071795864769f * (float)t * (1.0f/4096.0f));
        dft16<-1>(ur, ui);
        __syncthreads();
#pragma unroll
        for (int k=0;k<16;k++){
            const int slot = 4*(k&3) + (k>>2);
            sre[t + 256*k] = ur[slot];
            sim[t + 256*k] = ui[slot];
        }
    }
    __syncthreads();

    // ============ M1: hidden = relu(P1w @ [Re X ; Im X] + P1b), both rows ====
    {
        float h[16];
#pragma unroll
        for (int j=0;j<16;j++) h[j] = 0.0f;
#pragma unroll 4
        for (int k1=0;k1<16;k1++){
            const int k   = t + 256*k1;
            const int rev = (S_LEN - k) & (S_LEN - 1);
            const float ZkR = sre[k],   ZkI = sim[k];
            const float ZrR = sre[rev], ZrI = sim[rev];
            const float XaR = 0.5f*(ZkR + ZrR), XaI = 0.5f*(ZkI - ZrI);
            const float XbR = 0.5f*(ZkI + ZrI), XbI = 0.5f*(ZrR - ZkR);
#pragma unroll
            for (int r=0;r<RANK;r++){
                const float w1 = P1w[r * (2*S_LEN) + k];
                const float w2 = P1w[r * (2*S_LEN) + S_LEN + k];
                h[r]     += XaR * w1 + XaI * w2;
                h[8 + r] += XbR * w1 + XbI * w2;
            }
        }
#pragma unroll
        for (int j=0;j<16;j++){
#pragma unroll
            for (int off = 32; off > 0; off >>= 1)
                h[j] += __shfl_xor(h[j], off, 64);
        }
        if (lane == 0){
#pragma unroll
            for (int j=0;j<16;j++) red[wid*16 + j] = h[j];
        }
        __syncthreads();
        if (t < 16){
            float v = red[t] + red[16 + t] + red[32 + t] + red[48 + t];
            hid[t] = fmaxf(v + P1b[t & 7], 0.0f);
        }
        __syncthreads();
    }

    // ============ M2: gains + p/q rank-8 accumulation, wave-split rows =======
    // waves 0-1: row a over all k; waves 2-3: row b over all k.
    {
        float hh[RANK];
#pragma unroll
        for (int r=0;r<RANK;r++) hh[r] = rfl(hid[half*8 + r]);   // SGPR-resident

        float acc[32];   // [pR x8, pI x8, qR x8, qI x8] for my row
#pragma unroll
        for (int j=0;j<32;j++) acc[j] = 0.0f;

#pragma unroll 4
        for (int k1=0;k1<32;k1++){
            const int k   = th + 128*k1;
            const int rev = (S_LEN - k) & (S_LEN - 1);
            const float ZkR = sre[k],   ZkI = sim[k];
            const float ZrR = sre[rev], ZrI = sim[rev];
            float XR, XI;
            if (half == 0){ XR = 0.5f*(ZkR + ZrR); XI = 0.5f*(ZkI - ZrI); }
            else          { XR = 0.5f*(ZkI + ZrI); XI = 0.5f*(ZrR - ZkR); }

            float bg, fr; int lo, hi;
            gain_setup(k, bg, lo, hi, fr);

            const float4* p2lo = (const float4*)(P2w + (size_t)lo * RANK);
            const float4* p2hi = (const float4*)(P2w + (size_t)hi * RANK);
            const float4 a0 = p2lo[0], a1 = p2lo[1];
            const float4 b0 = p2hi[0], b1 = p2hi[1];
            const float dlo = P2b[lo] + hh[0]*a0.x + hh[1]*a0.y + hh[2]*a0.z + hh[3]*a0.w
                                      + hh[4]*a1.x + hh[5]*a1.y + hh[6]*a1.z + hh[7]*a1.w;
            const float dhi = P2b[hi] + hh[0]*b0.x + hh[1]*b0.y + hh[2]*b0.z + hh[3]*b0.w
                                      + hh[4]*b1.x + hh[5]*b1.y + hh[6]*b1.z + hh[7]*b1.w;
            const float g = fmaxf(bg + alpha * (dlo + (dhi - dlo) * fr), 0.0f);

            const float zR = g * XR, zI = g * XI;

#pragma unroll
            for (int r=0;r<RANK;r++){
                const float uR = Ur[r * S_LEN + k], uI = Ui[r * S_LEN + k];
                const float vR = Vr[r * S_LEN + k], vI = Vi[r * S_LEN + k];
                acc[r]      += zR * uR - zI * uI;
                acc[8 + r]  += zR * uI + zI * uR;
                acc[16 + r] += zR * vR - zI * vI;
                acc[24 + r] += zR * vI + zI * vR;
            }
        }

#pragma unroll
        for (int j=0;j<32;j++){
#pragma unroll
            for (int off = 32; off > 0; off >>= 1)
                acc[j] += __shfl_xor(acc[j], off, 64);
        }
        if (lane == 0){
#pragma unroll
            for (int j=0;j<32;j++) red[wid*32 + j] = acc[j];
        }
        __syncthreads();
        if (t < RANK){
            // row a: waves 0 (red[0..31]) + 1 (red[32..63])
            const float pR = red[t]      + red[32 + t];
            const float pI = red[8 + t]  + red[40 + t];
            const float qR = red[16 + t] + red[48 + t];
            const float qI = red[24 + t] + red[56 + t];
            gam[t]     = pR * qR + pI * qI;   // Re gamma_a
            gam[8 + t] = pI * qR - pR * qI;   // Im gamma_a
        } else if (t < 2 * RANK){
            const int j = t - RANK;
            // row b: waves 2 (red[64..95]) + 3 (red[96..127])
            const float pR = red[64 + j] + red[96 + j];
            const float pI = red[72 + j] + red[104 + j];
            const float qR = red[80 + j] + red[112 + j];
            const float qI = red[88 + j] + red[120 + j];
            gam[16 + j] = pR * qR + pI * qI;  // Re gamma_b
            gam[24 + j] = pI * qR - pR * qI;  // Im gamma_b
        }
        __syncthreads();
    }

    // ============ M4: w = za + i*zb + HermDa + i*HermDb (gains recomputed) ===
    {
        float hA[RANK], hB[RANK];
        float gaR[RANK], gaI[RANK], gbR[RANK], gbI[RANK];
#pragma unroll
        for (int r=0;r<RANK;r++){
            hA[r]  = rfl(hid[r]);
            hB[r]  = rfl(hid[8 + r]);
            gaR[r] = rfl(gam[r]);      gaI[r] = rfl(gam[8 + r]);
            gbR[r] = rfl(gam[16 + r]); gbI[r] = rfl(gam[24 + r]);
        }
        const float4* Wr4 = (const float4*)Wr;
        const float4* Wi4 = (const float4*)Wi;

#pragma unroll 2
        for (int k1=0;k1<16;k1++){
            const int k   = t + 256*k1;
            const int rev = (S_LEN - k) & (S_LEN - 1);
            const float ZkR = sre[k],   ZkI = sim[k];
            const float ZrR = sre[rev], ZrI = sim[rev];
            const float XaR = 0.5f*(ZkR + ZrR), XaI = 0.5f*(ZkI - ZrI);
            const float XbR = 0.5f*(ZkI + ZrI), XbI = 0.5f*(ZrR - ZkR);

            float bg, fr; int lo, hi;
            gain_setup(k, bg, lo, hi, fr);
            const float4* p2lo = (const float4*)(P2w + (size_t)lo * RANK);
            const float4* p2hi = (const float4*)(P2w + (size_t)hi * RANK);
            const float4 a0 = p2lo[0], a1 = p2lo[1];
            const float4 b0 = p2hi[0], b1 = p2hi[1];
            const float blo = P2b[lo], bhi = P2b[hi];
            const float dloA = blo + hA[0]*a0.x + hA[1]*a0.y + hA[2]*a0.z + hA[3]*a0.w
                                   + hA[4]*a1.x + hA[5]*a1.y + hA[6]*a1.z + hA[7]*a1.w;
            const float dhiA = bhi + hA[0]*b0.x + hA[1]*b0.y + hA[2]*b0.z + hA[3]*b0.w
                                   + hA[4]*b1.x + hA[5]*b1.y + hA[6]*b1.z + hA[7]*b1.w;
            const float dloB = blo + hB[0]*a0.x + hB[1]*a0.y + hB[2]*a0.z + hB[3]*a0.w
                                   + hB[4]*a1.x + hB[5]*a1.y + hB[6]*a1.z + hB[7]*a1.w;
            const float dhiB = bhi + hB[0]*b0.x + hB[1]*b0.y + hB[2]*b0.z + hB[3]*b0.w
                                   + hB[4]*b1.x + hB[5]*b1.y + hB[6]*b1.z + hB[7]*b1.w;
            const float ga = fmaxf(bg + alpha * (dloA + (dhiA - dloA) * fr), 0.0f);
            const float gb = fmaxf(bg + alpha * (dloB + (dhiB - dloB) * fr), 0.0f);

            // wgain = za + i*zb  (za = ga*Xa, zb = gb*Xb, both Hermitian)
            float wR = ga * XaR - gb * XbI;
            float wI = ga * XaI + gb * XbR;

            const float4 ka0 = Wr4[k*2],   ka1 = Wr4[k*2+1];
            const float4 kb0 = Wi4[k*2],   kb1 = Wi4[k*2+1];
            const float4 ra0 = Wr4[rev*2], ra1 = Wr4[rev*2+1];
            const float4 rb0 = Wi4[rev*2], rb1 = Wi4[rev*2+1];
            const float wrk[RANK] = { ka0.x,ka0.y,ka0.z,ka0.w, ka1.x,ka1.y,ka1.z,ka1.w };
            const float wik[RANK] = { kb0.x,kb0.y,kb0.z,kb0.w, kb1.x,kb1.y,kb1.z,kb1.w };
            const float wrr[RANK] = { ra0.x,ra0.y,ra0.z,ra0.w, ra1.x,ra1.y,ra1.z,ra1.w };
            const float wir[RANK] = { rb0.x,rb0.y,rb0.z,rb0.w, rb1.x,rb1.y,rb1.z,rb1.w };

            float aR=0.f, aI=0.f, arR=0.f, arI=0.f;
            float bR=0.f, bI=0.f, brR=0.f, brI=0.f;
#pragma unroll
            for (int r=0;r<RANK;r++){
                aR  += gaR[r]*wrk[r] - gaI[r]*wik[r];
                aI  += gaR[r]*wik[r] + gaI[r]*wrk[r];
                arR += gaR[r]*wrr[r] - gaI[r]*wir[r];
                arI += gaR[r]*wir[r] + gaI[r]*wrr[r];
                bR  += gbR[r]*wrk[r] - gbI[r]*wik[r];
                bI  += gbR[r]*wik[r] + gbI[r]*wrk[r];
                brR += gbR[r]*wrr[r] - gbI[r]*wir[r];
                brI += gbR[r]*wir[r] + gbI[r]*wrr[r];
            }
            // HermDa(k) = ((aR+arR)/2, (aI-arI)/2); HermDb likewise
            wR += 0.5f * (aR + arR) - 0.5f * (bI - brI);
            wI += 0.5f * (aI - arI) + 0.5f * (bR + brR);
            ur[k1] = wR;
            ui[k1] = wI;
        }
    }

    // ============ inverse FFT of w: row a = Re, row b = Im ====================
    dft16<1>(ur, ui);
    __syncthreads();   // all Z reads done before scratch overwrite
    {
        const int base1 = (t & 15) + 272 * (t >> 4);
#pragma unroll
        for (int k=0;k<16;k++){
            const int slot = 4*(k&3) + (k>>2);
            sre[base1 + 16*k] = ur[slot];
            sim[base1 + 16*k] = ui[slot];
        }
    }
    __syncthreads();
    {
        const int a = t & 15, b = t >> 4;
#pragma unroll
        for (int m=0;m<16;m++){
            ur[m] = sre[a + 272*m + 16*b];
            ui[m] = sim[a + 272*m + 16*b];
        }
        twiddle_powers<1>(ur, ui, 6.2831853071795864769f * (float)b * (1.0f/256.0f));
        dft16<1>(ur, ui);
        __syncthreads();
        const int base2 = b + 17*a;
#pragma unroll
        for (int k=0;k<16;k++){
            const int slot = 4*(k&3) + (k>>2);
            sre[base2 + 272*k] = ur[slot];
            sim[base2 + 272*k] = ui[slot];
        }
    }
    __syncthreads();
    {
#pragma unroll
        for (int m=0;m<16;m++){
            ur[m] = sre[(t&15) + 17*m + 272*(t>>4)];
            ui[m] = sim[(t&15) + 17*m + 272*(t>>4)];
        }
        twiddle_powers<1>(ur, ui, 6.2831853071795864769f * (float)t * (1.0f/4096.0f));
        dft16<1>(ur, ui);
        float* orowA = out + (size_t)(2 * pair) * S_LEN;
        float* orowB = orowA + S_LEN;
        const float scale = 1.0f / (float)S_LEN;
#pragma unroll
        for (int k=0;k<16;k++){
            const int slot = 4*(k&3) + (k>>2);
            orowA[t + 256*k] = ur[slot] * scale;
            orowB[t + 256*k] = ui[slot] * scale;
        }
    }
}

extern "C" void kernel_launch(void* const* d_in, const int* in_sizes, int n_in,
                              void* d_out, int out_size, void* d_ws, size_t ws_size,
                              hipStream_t stream) {
    const float* x    = (const float*)d_in[0];
    const float* Ur   = (const float*)d_in[1];
    const float* Ui   = (const float*)d_in[2];
    const float* Vr   = (const float*)d_in[3];
    const float* Vi   = (const float*)d_in[4];
    const float* Wr   = (const float*)d_in[5];
    const float* Wi   = (const float*)d_in[6];
    const float* P1w  = (const float*)d_in[7];
    const float* P1b  = (const float*)d_in[8];
    const float* P2w  = (const float*)d_in[9];
    const float* P2b  = (const float*)d_in[10];
    const float* alph = (const float*)d_in[11];

    recip_mixer<<<dim3(1024), dim3(NT), 0, stream>>>(
        x, Ur, Ui, Vr, Vi, Wr, Wi, P1w, P1b, P2w, P2b, alph, (float*)d_out);
}